// Round 4
// baseline (258.596 us; speedup 1.0000x reference)
//
#include <hip/hip_runtime.h>
#include <hip/hip_cooperative_groups.h>
#include <math.h>

namespace cg = cooperative_groups;

#define N 4096
#define P 128
#define H 4
#define E 32
#define NSEG 32
#define NBLK 256        // cooperative grid: 1 block per CU
#define TPB 256
#define PROJ_TASKS 384  // 128 row-tiles x 3 matrices
#define CH 96           // attn K/V chunk rows (24 KB LDS)
#define SPLIT 2

// ---------------------------------------------------------------------------
// Phase: counting sort (single block, LDS atomics). sm needs >= 97 ints.
// ---------------------------------------------------------------------------
__device__ __forceinline__ void sort_phase(const int* __restrict__ pos,
                                           int* __restrict__ seg_rows,
                                           int* __restrict__ seg_off,
                                           int* sm, int t) {
    int* cnt = sm;
    int* cur = sm + NSEG;
    int* off = sm + 2 * NSEG;   // NSEG+1
    if (t < NSEG) cnt[t] = 0;
    __syncthreads();
    for (int i = t; i < N; i += TPB) atomicAdd(&cnt[pos[i]], 1);
    __syncthreads();
    if (t == 0) {
        int s = 0;
        for (int k = 0; k < NSEG; ++k) { off[k] = s; s += cnt[k]; }
        off[NSEG] = s;
    }
    __syncthreads();
    if (t <= NSEG) seg_off[t] = off[t];
    if (t < NSEG) cur[t] = off[t];
    __syncthreads();
    for (int i = t; i < N; i += TPB) {
        int r = atomicAdd(&cur[pos[i]], 1);
        seg_rows[r] = i;
    }
    __syncthreads();
}

// ---------------------------------------------------------------------------
// Phase: one 32-row QKV projection tile. task in [0,384): tile=task&127,
// mat=task>>7. sm: Xl = sm[0..4095], Wl = sm[4096..8191] (32 KB).
// ---------------------------------------------------------------------------
__device__ __forceinline__ void proj_phase(int task,
                                           const float* __restrict__ x,
                                           const float* __restrict__ Wq, const float* __restrict__ bq,
                                           const float* __restrict__ Wk, const float* __restrict__ bk,
                                           const float* __restrict__ Wv, const float* __restrict__ bv,
                                           float* __restrict__ Q, float* __restrict__ Ko, float* __restrict__ Vo,
                                           float* sm, int t) {
    float* Xl = sm;           // [32][128]
    float* Wl = sm + 4096;    // [32][128]

    const int mat = task >> 7;
    const int r0  = (task & 127) * 32;
    const float* W = (mat == 0) ? Wq : (mat == 1) ? Wk : Wv;
    const float* b = (mat == 0) ? bq : (mat == 1) ? bk : bv;
    float* y       = (mat == 0) ? Q  : (mat == 1) ? Ko : Vo;

    for (int i = t * 4; i < 32 * 128; i += TPB * 4) {
        *(float4*)(Xl + i) = *(const float4*)(x + (size_t)r0 * 128 + i);
    }

    const int tc = t & 31;   // cols 4*tc..4*tc+3
    const int tr = t >> 5;   // rows 4*tr..4*tr+3

    float4 bb = *(const float4*)(b + tc * 4);
    float4 acc[4];
#pragma unroll
    for (int r = 0; r < 4; ++r) acc[r] = bb;

    for (int kc = 0; kc < 128; kc += 32) {
        __syncthreads();
        for (int i = t * 4; i < 32 * 128; i += TPB * 4) {
            *(float4*)(Wl + i) = *(const float4*)(W + (size_t)kc * 128 + i);
        }
        __syncthreads();
#pragma unroll
        for (int k0 = 0; k0 < 32; k0 += 4) {
            float4 w0 = *(float4*)&Wl[(k0 + 0) * 128 + tc * 4];
            float4 w1 = *(float4*)&Wl[(k0 + 1) * 128 + tc * 4];
            float4 w2 = *(float4*)&Wl[(k0 + 2) * 128 + tc * 4];
            float4 w3 = *(float4*)&Wl[(k0 + 3) * 128 + tc * 4];
#pragma unroll
            for (int r = 0; r < 4; ++r) {
                float4 xv = *(float4*)&Xl[(tr * 4 + r) * 128 + kc + k0];
                acc[r].x = fmaf(xv.x, w0.x, acc[r].x);
                acc[r].y = fmaf(xv.x, w0.y, acc[r].y);
                acc[r].z = fmaf(xv.x, w0.z, acc[r].z);
                acc[r].w = fmaf(xv.x, w0.w, acc[r].w);
                acc[r].x = fmaf(xv.y, w1.x, acc[r].x);
                acc[r].y = fmaf(xv.y, w1.y, acc[r].y);
                acc[r].z = fmaf(xv.y, w1.z, acc[r].z);
                acc[r].w = fmaf(xv.y, w1.w, acc[r].w);
                acc[r].x = fmaf(xv.z, w2.x, acc[r].x);
                acc[r].y = fmaf(xv.z, w2.y, acc[r].y);
                acc[r].z = fmaf(xv.z, w2.z, acc[r].z);
                acc[r].w = fmaf(xv.z, w2.w, acc[r].w);
                acc[r].x = fmaf(xv.w, w3.x, acc[r].x);
                acc[r].y = fmaf(xv.w, w3.y, acc[r].y);
                acc[r].z = fmaf(xv.w, w3.z, acc[r].z);
                acc[r].w = fmaf(xv.w, w3.w, acc[r].w);
            }
        }
    }

#pragma unroll
    for (int r = 0; r < 4; ++r) {
        *(float4*)(y + (size_t)(r0 + tr * 4 + r) * 128 + tc * 4) = acc[r];
    }
    __syncthreads();   // Xl reused by the next task iteration
}

// ---------------------------------------------------------------------------
// Phase: split-K attention for block id b = (s<<3)|(h<<1)|sp.
// 2 lanes per query (E halves), shfl-xor dot reduce, online softmax.
// sm: Ks = sm[0..CH*E), Vs = sm[CH*E..2*CH*E)  (24 KB).
// ---------------------------------------------------------------------------
__device__ __forceinline__ void attn_phase(int b,
                                           const float* __restrict__ Q,
                                           const float* __restrict__ K,
                                           const float* __restrict__ V,
                                           const int* __restrict__ seg_rows,
                                           const int* __restrict__ seg_off,
                                           float2* __restrict__ pml,
                                           float* __restrict__ pacc,
                                           float* sm, int t) {
    float* Ks = sm;
    float* Vs = sm + CH * E;

    const int s   = b >> 3;
    const int h   = (b >> 1) & 3;
    const int sp  = b & 1;
    const int beg = seg_off[s];
    const int len = seg_off[s + 1] - beg;
    const float scale = 0.17677669529663687f;   // 1/sqrt(32)

    const int k0 = (len * sp) >> 1;
    const int k1 = (len * (sp + 1)) >> 1;
    const int sl = k1 - k0;

    const int qq = t >> 1;   // query slot
    const int hf = t & 1;    // E half

    for (int qb = 0; qb < len; qb += TPB / 2) {
        const int  qi     = qb + qq;
        const bool active = (qi < len);
        const int  qrow   = active ? seg_rows[beg + qi] : 0;

        float q[16];
        if (active) {
            const float* qp = Q + (size_t)qrow * P + h * E + hf * 16;
#pragma unroll
            for (int e = 0; e < 16; e += 4) {
                float4 v4 = *(const float4*)(qp + e);
                q[e] = v4.x; q[e + 1] = v4.y; q[e + 2] = v4.z; q[e + 3] = v4.w;
            }
        }

        float m = -3.0e38f, l = 0.f;
        float acc[16];
#pragma unroll
        for (int e = 0; e < 16; ++e) acc[e] = 0.f;

        for (int cb = 0; cb < sl; cb += CH) {
            const int cl = min(CH, sl - cb);
            __syncthreads();
            for (int idx = t; idx < cl * E; idx += TPB) {
                int r = idx >> 5, e = idx & 31;
                int krow = seg_rows[beg + k0 + cb + r];
                Ks[r * E + e] = K[(size_t)krow * P + h * E + e];
                Vs[r * E + e] = V[(size_t)krow * P + h * E + e];
            }
            __syncthreads();
            if (active) {
                for (int r = 0; r < cl; ++r) {
                    const float* kr = Ks + r * E + hf * 16;
                    float4 a0 = *(const float4*)(kr);
                    float4 a1 = *(const float4*)(kr + 4);
                    float4 a2 = *(const float4*)(kr + 8);
                    float4 a3 = *(const float4*)(kr + 12);
                    float d0 = q[0] * a0.x + q[8]  * a2.x;
                    float d1 = q[1] * a0.y + q[9]  * a2.y;
                    float d2 = q[2] * a0.z + q[10] * a2.z;
                    float d3 = q[3] * a0.w + q[11] * a2.w;
                    d0 = fmaf(q[4],  a1.x, d0); d1 = fmaf(q[5],  a1.y, d1);
                    d2 = fmaf(q[6],  a1.z, d2); d3 = fmaf(q[7],  a1.w, d3);
                    d0 = fmaf(q[12], a3.x, d0); d1 = fmaf(q[13], a3.y, d1);
                    d2 = fmaf(q[14], a3.z, d2); d3 = fmaf(q[15], a3.w, d3);
                    float d = (d0 + d1) + (d2 + d3);
                    d += __shfl_xor(d, 1);           // pair-reduce (both lanes identical)
                    float sc = d * scale;

                    float mn   = fmaxf(m, sc);
                    float corr = __expf(m - mn);
                    float p    = __expf(sc - mn);
                    l = l * corr + p;
                    const float* vr = Vs + r * E + hf * 16;
#pragma unroll
                    for (int e = 0; e < 16; ++e)
                        acc[e] = fmaf(p, vr[e], acc[e] * corr);
                    m = mn;
                }
            }
        }

        if (active) {
            const size_t pidx = ((size_t)(beg + qi) * H + h) * SPLIT + sp;
            if (hf == 0) pml[pidx] = make_float2(m, l);
            float* pa = pacc + pidx * E + hf * 16;
#pragma unroll
            for (int e = 0; e < 16; e += 4) {
                *(float4*)(pa + e) = make_float4(acc[e], acc[e + 1], acc[e + 2], acc[e + 3]);
            }
        }
    }
    __syncthreads();
}

// ---------------------------------------------------------------------------
// Phase: merge SPLIT=2 partials for pair p = sIdx*H + h.
// ---------------------------------------------------------------------------
__device__ __forceinline__ void merge_phase(int p,
                                            const float2* __restrict__ pml,
                                            const float* __restrict__ pacc,
                                            const int* __restrict__ seg_rows,
                                            float* __restrict__ out) {
    const int sIdx = p >> 2;
    const int h    = p & 3;
    const size_t base = ((size_t)sIdx * H + h) * SPLIT;
    float2 ml0 = pml[base];
    float2 ml1 = pml[base + 1];
    float m  = fmaxf(ml0.x, ml1.x);
    float w0 = __expf(ml0.x - m);
    float w1 = __expf(ml1.x - m);
    float inv = 1.0f / (ml0.y * w0 + ml1.y * w1);
    const int row = seg_rows[sIdx];
    const float* p0 = pacc + base * E;
    const float* p1 = pacc + (base + 1) * E;
#pragma unroll
    for (int e = 0; e < E; e += 4) {
        float4 x0 = *(const float4*)(p0 + e);
        float4 x1 = *(const float4*)(p1 + e);
        float4 o;
        o.x = (x0.x * w0 + x1.x * w1) * inv;
        o.y = (x0.y * w0 + x1.y * w1) * inv;
        o.z = (x0.z * w0 + x1.z * w1) * inv;
        o.w = (x0.w * w0 + x1.w * w1) * inv;
        *(float4*)(out + (size_t)row * P + h * E + e) = o;
    }
}

// ---------------------------------------------------------------------------
// Fused cooperative kernel: sort||proj -> grid.sync -> attn -> grid.sync -> merge
// ---------------------------------------------------------------------------
__global__ __launch_bounds__(TPB) void fused_kernel(
        const float* __restrict__ inp, const int* __restrict__ pos,
        const float* __restrict__ Wq, const float* __restrict__ bq,
        const float* __restrict__ Wk, const float* __restrict__ bk,
        const float* __restrict__ Wv, const float* __restrict__ bv,
        float* __restrict__ Q, float* __restrict__ Kb, float* __restrict__ Vb,
        int* __restrict__ seg_rows, int* __restrict__ seg_off,
        float2* __restrict__ pml, float* __restrict__ pacc,
        float* __restrict__ out) {
    __shared__ __align__(16) float sm[8192];   // 32 KB, phase-overlaid
    const int t = threadIdx.x;
    const int b = blockIdx.x;

    // Phase 0+1: block 0 sorts; blocks 1..255 do the 384 projection tiles.
    if (b == 0) {
        sort_phase(pos, seg_rows, seg_off, (int*)sm, t);
    } else {
        for (int task = b - 1; task < PROJ_TASKS; task += NBLK - 1)
            proj_phase(task, inp, Wq, bq, Wk, bk, Wv, bv, Q, Kb, Vb, sm, t);
    }
    __threadfence();
    cg::this_grid().sync();

    // Phase 2: split-K attention (one (s,h,sp) triple per block).
    attn_phase(b, Q, Kb, Vb, seg_rows, seg_off, pml, pacc, sm, t);
    __threadfence();
    cg::this_grid().sync();

    // Phase 3: merge partials.
    for (int p = b * TPB + t; p < N * H; p += NBLK * TPB)
        merge_phase(p, pml, pacc, seg_rows, out);
}

// ---------------------------------------------------------------------------
// Fallback wrappers (used only if cooperative launch is rejected).
// ---------------------------------------------------------------------------
__global__ __launch_bounds__(TPB) void sort_kernel_w(const int* __restrict__ pos,
                                                     int* __restrict__ seg_rows,
                                                     int* __restrict__ seg_off) {
    __shared__ int sm[2 * NSEG + NSEG + 1];
    sort_phase(pos, seg_rows, seg_off, sm, threadIdx.x);
}

__global__ __launch_bounds__(TPB) void proj_kernel_w(const float* __restrict__ inp,
        const float* __restrict__ Wq, const float* __restrict__ bq,
        const float* __restrict__ Wk, const float* __restrict__ bk,
        const float* __restrict__ Wv, const float* __restrict__ bv,
        float* __restrict__ Q, float* __restrict__ Kb, float* __restrict__ Vb) {
    __shared__ __align__(16) float sm[8192];
    proj_phase(blockIdx.x, inp, Wq, bq, Wk, bk, Wv, bv, Q, Kb, Vb, sm, threadIdx.x);
}

__global__ __launch_bounds__(TPB) void attn_kernel_w(const float* __restrict__ Q,
        const float* __restrict__ Kb, const float* __restrict__ Vb,
        const int* __restrict__ seg_rows, const int* __restrict__ seg_off,
        float2* __restrict__ pml, float* __restrict__ pacc) {
    __shared__ __align__(16) float sm[2 * CH * E];
    attn_phase(blockIdx.x, Q, Kb, Vb, seg_rows, seg_off, pml, pacc, sm, threadIdx.x);
}

__global__ __launch_bounds__(TPB) void merge_kernel_w(const float2* __restrict__ pml,
        const float* __restrict__ pacc, const int* __restrict__ seg_rows,
        float* __restrict__ out) {
    merge_phase(blockIdx.x * TPB + threadIdx.x, pml, pacc, seg_rows, out);
}

// ---------------------------------------------------------------------------
extern "C" void kernel_launch(void* const* d_in, const int* in_sizes, int n_in,
                              void* d_out, int out_size, void* d_ws, size_t ws_size,
                              hipStream_t stream) {
    const float* inp = (const float*)d_in[0];
    const int*   pos = (const int*)d_in[1];
    const float* Wq  = (const float*)d_in[2];
    const float* bq  = (const float*)d_in[3];
    const float* Wk  = (const float*)d_in[4];
    const float* bk  = (const float*)d_in[5];
    const float* Wv  = (const float*)d_in[6];
    const float* bv  = (const float*)d_in[7];
    float* out = (float*)d_out;

    // workspace layout
    float* Q  = (float*)d_ws;
    float* Kb = Q + (size_t)N * P;
    float* Vb = Kb + (size_t)N * P;
    int* seg_rows = (int*)(Vb + (size_t)N * P);
    int* seg_off  = seg_rows + N;          // NSEG+1
    char* after = (char*)(seg_off + NSEG + 1);
    size_t used = ((size_t)(after - (char*)d_ws) + 15) & ~(size_t)15;
    float2* pml = (float2*)((char*)d_ws + used);
    float*  pacc = (float*)(pml + (size_t)N * H * SPLIT);

    void* kargs[] = {
        (void*)&inp, (void*)&pos,
        (void*)&Wq, (void*)&bq, (void*)&Wk, (void*)&bk, (void*)&Wv, (void*)&bv,
        (void*)&Q, (void*)&Kb, (void*)&Vb,
        (void*)&seg_rows, (void*)&seg_off,
        (void*)&pml, (void*)&pacc, (void*)&out
    };

    hipError_t err = hipLaunchCooperativeKernel((const void*)fused_kernel,
                                                dim3(NBLK), dim3(TPB),
                                                kargs, 0, stream);
    if (err != hipSuccess) {
        // fallback: same phases as 4 plain dispatches
        sort_kernel_w<<<1, TPB, 0, stream>>>(pos, seg_rows, seg_off);
        proj_kernel_w<<<PROJ_TASKS, TPB, 0, stream>>>(inp, Wq, bq, Wk, bk, Wv, bv, Q, Kb, Vb);
        attn_kernel_w<<<NBLK, TPB, 0, stream>>>(Q, Kb, Vb, seg_rows, seg_off, pml, pacc);
        merge_kernel_w<<<N * H / TPB, TPB, 0, stream>>>(pml, pacc, seg_rows, out);
    }
}

// Round 5
// 148.156 us; speedup vs baseline: 1.7454x; 1.7454x over previous
//
#include <hip/hip_runtime.h>
#include <math.h>

#define N 4096
#define P 128
#define H 4
#define E 32
#define NSEG 32
#define TPB 256
#define PROJ_TASKS 384   // 128 row-tiles x 3 matrices

// attention config: split-Q, direct output write (no merge pass)
#define QS 4             // query splits per (seg, head)
#define ATPB 128         // attn block threads: 32 query slots x 4 lanes
#define CH 128           // K/V chunk rows staged in LDS (32 KB)

// ---------------------------------------------------------------------------
// Phase: counting sort (single block, LDS atomics).
// ---------------------------------------------------------------------------
__device__ __forceinline__ void sort_phase(const int* __restrict__ pos,
                                           int* __restrict__ seg_rows,
                                           int* __restrict__ seg_off,
                                           int* sm, int t) {
    int* cnt = sm;              // NSEG
    int* cur = sm + NSEG;       // NSEG
    int* off = sm + 2 * NSEG;   // NSEG+1
    if (t < NSEG) cnt[t] = 0;
    __syncthreads();
    for (int i = t; i < N; i += TPB) atomicAdd(&cnt[pos[i]], 1);
    __syncthreads();
    if (t == 0) {
        int s = 0;
        for (int k = 0; k < NSEG; ++k) { off[k] = s; s += cnt[k]; }
        off[NSEG] = s;
    }
    __syncthreads();
    if (t <= NSEG) seg_off[t] = off[t];
    if (t < NSEG) cur[t] = off[t];
    __syncthreads();
    for (int i = t; i < N; i += TPB) {
        int r = atomicAdd(&cur[pos[i]], 1);
        seg_rows[r] = i;
    }
}

// ---------------------------------------------------------------------------
// Phase: one 32-row QKV projection tile. task in [0,384): tile=task&127,
// mat=task>>7. sm: Xl = sm[0..4095], Wl = sm[4096..8191] (32 KB).
// ---------------------------------------------------------------------------
__device__ __forceinline__ void proj_phase(int task,
                                           const float* __restrict__ x,
                                           const float* __restrict__ Wq, const float* __restrict__ bq,
                                           const float* __restrict__ Wk, const float* __restrict__ bk,
                                           const float* __restrict__ Wv, const float* __restrict__ bv,
                                           float* __restrict__ Q, float* __restrict__ Ko, float* __restrict__ Vo,
                                           float* sm, int t) {
    float* Xl = sm;           // [32][128]
    float* Wl = sm + 4096;    // [32][128]

    const int mat = task >> 7;
    const int r0  = (task & 127) * 32;
    const float* W = (mat == 0) ? Wq : (mat == 1) ? Wk : Wv;
    const float* b = (mat == 0) ? bq : (mat == 1) ? bk : bv;
    float* y       = (mat == 0) ? Q  : (mat == 1) ? Ko : Vo;

    for (int i = t * 4; i < 32 * 128; i += TPB * 4) {
        *(float4*)(Xl + i) = *(const float4*)(x + (size_t)r0 * 128 + i);
    }

    const int tc = t & 31;   // cols 4*tc..4*tc+3
    const int tr = t >> 5;   // rows 4*tr..4*tr+3

    float4 bb = *(const float4*)(b + tc * 4);
    float4 acc[4];
#pragma unroll
    for (int r = 0; r < 4; ++r) acc[r] = bb;

    for (int kc = 0; kc < 128; kc += 32) {
        __syncthreads();
        for (int i = t * 4; i < 32 * 128; i += TPB * 4) {
            *(float4*)(Wl + i) = *(const float4*)(W + (size_t)kc * 128 + i);
        }
        __syncthreads();
#pragma unroll
        for (int k0 = 0; k0 < 32; k0 += 4) {
            float4 w0 = *(float4*)&Wl[(k0 + 0) * 128 + tc * 4];
            float4 w1 = *(float4*)&Wl[(k0 + 1) * 128 + tc * 4];
            float4 w2 = *(float4*)&Wl[(k0 + 2) * 128 + tc * 4];
            float4 w3 = *(float4*)&Wl[(k0 + 3) * 128 + tc * 4];
#pragma unroll
            for (int r = 0; r < 4; ++r) {
                float4 xv = *(float4*)&Xl[(tr * 4 + r) * 128 + kc + k0];
                acc[r].x = fmaf(xv.x, w0.x, acc[r].x);
                acc[r].y = fmaf(xv.x, w0.y, acc[r].y);
                acc[r].z = fmaf(xv.x, w0.z, acc[r].z);
                acc[r].w = fmaf(xv.x, w0.w, acc[r].w);
                acc[r].x = fmaf(xv.y, w1.x, acc[r].x);
                acc[r].y = fmaf(xv.y, w1.y, acc[r].y);
                acc[r].z = fmaf(xv.y, w1.z, acc[r].z);
                acc[r].w = fmaf(xv.y, w1.w, acc[r].w);
                acc[r].x = fmaf(xv.z, w2.x, acc[r].x);
                acc[r].y = fmaf(xv.z, w2.y, acc[r].y);
                acc[r].z = fmaf(xv.z, w2.z, acc[r].z);
                acc[r].w = fmaf(xv.z, w2.w, acc[r].w);
                acc[r].x = fmaf(xv.w, w3.x, acc[r].x);
                acc[r].y = fmaf(xv.w, w3.y, acc[r].y);
                acc[r].z = fmaf(xv.w, w3.z, acc[r].z);
                acc[r].w = fmaf(xv.w, w3.w, acc[r].w);
            }
        }
    }

#pragma unroll
    for (int r = 0; r < 4; ++r) {
        *(float4*)(y + (size_t)(r0 + tr * 4 + r) * 128 + tc * 4) = acc[r];
    }
}

// ---------------------------------------------------------------------------
// Dispatch 1: block 0 sorts; blocks 1..384 each do one projection tile.
// The two jobs are independent; attn (dispatch 2) consumes both via stream
// ordering — no grid sync anywhere.
// ---------------------------------------------------------------------------
__global__ __launch_bounds__(TPB) void sort_proj_kernel(
        const float* __restrict__ inp, const int* __restrict__ pos,
        const float* __restrict__ Wq, const float* __restrict__ bq,
        const float* __restrict__ Wk, const float* __restrict__ bk,
        const float* __restrict__ Wv, const float* __restrict__ bv,
        float* __restrict__ Q, float* __restrict__ Kb, float* __restrict__ Vb,
        int* __restrict__ seg_rows, int* __restrict__ seg_off) {
    __shared__ __align__(16) float sm[8192];   // 32 KB
    const int b = blockIdx.x;
    const int t = threadIdx.x;
    if (b == 0) {
        sort_phase(pos, seg_rows, seg_off, (int*)sm, t);
    } else {
        proj_phase(b - 1, inp, Wq, bq, Wk, bk, Wv, bv, Q, Kb, Vb, sm, t);
    }
}

// ---------------------------------------------------------------------------
// Dispatch 2: split-Q attention, direct output write.
// Grid (NSEG, H, QS), block 128 = 32 query slots x 4 lanes (E quarters).
// Online softmax per query over ALL keys of the segment; K/V staged to LDS
// in CH-row chunks; row ids staged through LDS to break the gather chain.
// ---------------------------------------------------------------------------
__global__ __launch_bounds__(ATPB) void attn_kernel(const float* __restrict__ Q,
                                                    const float* __restrict__ K,
                                                    const float* __restrict__ V,
                                                    const int* __restrict__ seg_rows,
                                                    const int* __restrict__ seg_off,
                                                    float* __restrict__ out) {
    __shared__ float Ks[CH * E];   // 16 KB
    __shared__ float Vs[CH * E];   // 16 KB
    __shared__ int   rid[CH];

    const int s   = blockIdx.x;
    const int h   = blockIdx.y;
    const int z   = blockIdx.z;
    const int beg = seg_off[s];
    const int len = seg_off[s + 1] - beg;
    const int t   = threadIdx.x;
    const float scale = 0.17677669529663687f;   // 1/sqrt(32)

    const int q0 = (int)(((long)len * z) / QS);
    const int q1 = (int)(((long)len * (z + 1)) / QS);

    const int ql = t & 3;    // E quarter: elements ql*8 .. ql*8+7
    const int qq = t >> 2;   // query slot in [0,32)

    const int nb = (q1 - q0 + 31) >> 5;   // query batches (uniform)

    for (int b2 = 0; b2 < nb; ++b2) {
        const int  qi     = q0 + b2 * 32 + qq;
        const bool active = (qi < q1);
        const int  qrow   = active ? seg_rows[beg + qi] : 0;

        float q[8];
        if (active) {
            const float* qp = Q + (size_t)qrow * P + h * E + ql * 8;
            float4 v0 = *(const float4*)(qp);
            float4 v1 = *(const float4*)(qp + 4);
            q[0] = v0.x; q[1] = v0.y; q[2] = v0.z; q[3] = v0.w;
            q[4] = v1.x; q[5] = v1.y; q[6] = v1.z; q[7] = v1.w;
        }

        float m = -3.0e38f, l = 0.f;
        float acc[8];
#pragma unroll
        for (int e = 0; e < 8; ++e) acc[e] = 0.f;

        for (int cb = 0; cb < len; cb += CH) {
            const int cl = min(CH, len - cb);
            __syncthreads();
            if (t < cl) rid[t] = seg_rows[beg + cb + t];
            __syncthreads();
            for (int idx = t; idx < cl * E; idx += ATPB) {
                const int r = idx >> 5, e = idx & 31;
                const int krow = rid[r];
                Ks[idx] = K[(size_t)krow * P + h * E + e];
                Vs[idx] = V[(size_t)krow * P + h * E + e];
            }
            __syncthreads();
            if (active) {
                for (int r = 0; r < cl; ++r) {
                    const float* kr = Ks + r * E + ql * 8;
                    float4 a0 = *(const float4*)(kr);
                    float4 a1 = *(const float4*)(kr + 4);
                    float d0 = q[0] * a0.x + q[4] * a1.x;
                    float d1 = q[1] * a0.y + q[5] * a1.y;
                    float d2 = q[2] * a0.z + q[6] * a1.z;
                    float d3 = q[3] * a0.w + q[7] * a1.w;
                    float d  = (d0 + d1) + (d2 + d3);
                    d += __shfl_xor(d, 1);
                    d += __shfl_xor(d, 2);      // all 4 lanes: full dot
                    const float sc = d * scale;

                    const float mn   = fmaxf(m, sc);
                    const float corr = __expf(m - mn);
                    const float p    = __expf(sc - mn);
                    l = l * corr + p;
                    const float* vr = Vs + r * E + ql * 8;
#pragma unroll
                    for (int e = 0; e < 8; ++e)
                        acc[e] = fmaf(p, vr[e], acc[e] * corr);
                    m = mn;
                }
            }
        }

        if (active) {
            const float inv = 1.0f / l;
            float* op = out + (size_t)qrow * P + h * E + ql * 8;
            *(float4*)(op)     = make_float4(acc[0] * inv, acc[1] * inv, acc[2] * inv, acc[3] * inv);
            *(float4*)(op + 4) = make_float4(acc[4] * inv, acc[5] * inv, acc[6] * inv, acc[7] * inv);
        }
    }
}

// ---------------------------------------------------------------------------
extern "C" void kernel_launch(void* const* d_in, const int* in_sizes, int n_in,
                              void* d_out, int out_size, void* d_ws, size_t ws_size,
                              hipStream_t stream) {
    const float* inp = (const float*)d_in[0];
    const int*   pos = (const int*)d_in[1];
    const float* Wq  = (const float*)d_in[2];
    const float* bq  = (const float*)d_in[3];
    const float* Wk  = (const float*)d_in[4];
    const float* bk  = (const float*)d_in[5];
    const float* Wv  = (const float*)d_in[6];
    const float* bv  = (const float*)d_in[7];
    float* out = (float*)d_out;

    // workspace layout: Q, K, V, seg_rows, seg_off
    float* Q  = (float*)d_ws;
    float* Kb = Q + (size_t)N * P;
    float* Vb = Kb + (size_t)N * P;
    int* seg_rows = (int*)(Vb + (size_t)N * P);
    int* seg_off  = seg_rows + N;          // NSEG+1

    sort_proj_kernel<<<1 + PROJ_TASKS, TPB, 0, stream>>>(
        inp, pos, Wq, bq, Wk, bk, Wv, bv, Q, Kb, Vb, seg_rows, seg_off);

    attn_kernel<<<dim3(NSEG, H, QS), ATPB, 0, stream>>>(
        Q, Kb, Vb, seg_rows, seg_off, out);
}

// Round 6
// 116.475 us; speedup vs baseline: 2.2202x; 1.2720x over previous
//
#include <hip/hip_runtime.h>
#include <math.h>

#define N 4096
#define P 128
#define H 4
#define E 32
#define NSEG 32
#define TPB 256

// proj: 64-row tiles x 3 matrices = 192 tasks (+1 sort block = 193 <= 256 CUs)
#define PROJ_TASKS 192

// attention: split-Q, group-batched online softmax
#define QS 3             // query splits per (seg, head) -> grid z
#define ATPB 256         // 64 query slots x 4 lanes
#define CH 128           // K/V rows staged per LDS chunk
#define G 8              // score group size (chain-breaking batch)
#define NEGF -3.0e38f

// ---------------------------------------------------------------------------
// Counting sort (single block, LDS atomics).
// ---------------------------------------------------------------------------
__device__ __forceinline__ void sort_phase(const int* __restrict__ pos,
                                           int* __restrict__ seg_rows,
                                           int* __restrict__ seg_off,
                                           int* sm, int t) {
    int* cnt = sm;              // NSEG
    int* cur = sm + NSEG;       // NSEG
    int* off = sm + 2 * NSEG;   // NSEG+1
    if (t < NSEG) cnt[t] = 0;
    __syncthreads();
    for (int i = t; i < N; i += TPB) atomicAdd(&cnt[pos[i]], 1);
    __syncthreads();
    if (t == 0) {
        int s = 0;
        for (int k = 0; k < NSEG; ++k) { off[k] = s; s += cnt[k]; }
        off[NSEG] = s;
    }
    __syncthreads();
    if (t <= NSEG) seg_off[t] = off[t];
    if (t < NSEG) cur[t] = off[t];
    __syncthreads();
    for (int i = t; i < N; i += TPB) {
        int r = atomicAdd(&cur[pos[i]], 1);
        seg_rows[r] = i;
    }
}

// ---------------------------------------------------------------------------
// One 64-row QKV projection tile. task in [0,192): mat=task>>6, tile=task&63.
// sm: Xl [64][128] (32KB) + Wl [32][128] (16KB) = 48KB.
// Each thread: 8-row x 4-col micro-tile.
// ---------------------------------------------------------------------------
__device__ __forceinline__ void proj_phase(int task,
                                           const float* __restrict__ x,
                                           const float* __restrict__ Wq, const float* __restrict__ bq,
                                           const float* __restrict__ Wk, const float* __restrict__ bk,
                                           const float* __restrict__ Wv, const float* __restrict__ bv,
                                           float* __restrict__ Q, float* __restrict__ Ko, float* __restrict__ Vo,
                                           float* sm, int t) {
    float* Xl = sm;           // [64][128]
    float* Wl = sm + 8192;    // [32][128]

    const int mat = task >> 6;
    const int r0  = (task & 63) * 64;
    const float* W = (mat == 0) ? Wq : (mat == 1) ? Wk : Wv;
    const float* b = (mat == 0) ? bq : (mat == 1) ? bk : bv;
    float* y       = (mat == 0) ? Q  : (mat == 1) ? Ko : Vo;

    for (int i = t * 4; i < 64 * 128; i += TPB * 4) {
        *(float4*)(Xl + i) = *(const float4*)(x + (size_t)r0 * 128 + i);
    }

    const int tc = t & 31;   // cols 4*tc..4*tc+3
    const int tr = t >> 5;   // rows 8*tr..8*tr+7

    float4 bb = *(const float4*)(b + tc * 4);
    float4 acc[8];
#pragma unroll
    for (int r = 0; r < 8; ++r) acc[r] = bb;

    for (int kc = 0; kc < 128; kc += 32) {
        __syncthreads();
        for (int i = t * 4; i < 32 * 128; i += TPB * 4) {
            *(float4*)(Wl + i) = *(const float4*)(W + (size_t)kc * 128 + i);
        }
        __syncthreads();
#pragma unroll
        for (int k0 = 0; k0 < 32; k0 += 4) {
            float4 w0 = *(float4*)&Wl[(k0 + 0) * 128 + tc * 4];
            float4 w1 = *(float4*)&Wl[(k0 + 1) * 128 + tc * 4];
            float4 w2 = *(float4*)&Wl[(k0 + 2) * 128 + tc * 4];
            float4 w3 = *(float4*)&Wl[(k0 + 3) * 128 + tc * 4];
#pragma unroll
            for (int r = 0; r < 8; ++r) {
                float4 xv = *(float4*)&Xl[(tr * 8 + r) * 128 + kc + k0];
                acc[r].x = fmaf(xv.x, w0.x, acc[r].x);
                acc[r].y = fmaf(xv.x, w0.y, acc[r].y);
                acc[r].z = fmaf(xv.x, w0.z, acc[r].z);
                acc[r].w = fmaf(xv.x, w0.w, acc[r].w);
                acc[r].x = fmaf(xv.y, w1.x, acc[r].x);
                acc[r].y = fmaf(xv.y, w1.y, acc[r].y);
                acc[r].z = fmaf(xv.y, w1.z, acc[r].z);
                acc[r].w = fmaf(xv.y, w1.w, acc[r].w);
                acc[r].x = fmaf(xv.z, w2.x, acc[r].x);
                acc[r].y = fmaf(xv.z, w2.y, acc[r].y);
                acc[r].z = fmaf(xv.z, w2.z, acc[r].z);
                acc[r].w = fmaf(xv.z, w2.w, acc[r].w);
                acc[r].x = fmaf(xv.w, w3.x, acc[r].x);
                acc[r].y = fmaf(xv.w, w3.y, acc[r].y);
                acc[r].z = fmaf(xv.w, w3.z, acc[r].z);
                acc[r].w = fmaf(xv.w, w3.w, acc[r].w);
            }
        }
    }

#pragma unroll
    for (int r = 0; r < 8; ++r) {
        *(float4*)(y + (size_t)(r0 + tr * 8 + r) * 128 + tc * 4) = acc[r];
    }
}

// ---------------------------------------------------------------------------
// Dispatch 1: block 0 sorts; blocks 1..192 each do one 64-row proj tile.
// ---------------------------------------------------------------------------
__global__ __launch_bounds__(TPB) void sort_proj_kernel(
        const float* __restrict__ inp, const int* __restrict__ pos,
        const float* __restrict__ Wq, const float* __restrict__ bq,
        const float* __restrict__ Wk, const float* __restrict__ bk,
        const float* __restrict__ Wv, const float* __restrict__ bv,
        float* __restrict__ Q, float* __restrict__ Kb, float* __restrict__ Vb,
        int* __restrict__ seg_rows, int* __restrict__ seg_off) {
    __shared__ __align__(16) float sm[12288];   // 48 KB
    const int b = blockIdx.x;
    const int t = threadIdx.x;
    if (b == 0) {
        sort_phase(pos, seg_rows, seg_off, (int*)sm, t);
    } else {
        proj_phase(b - 1, inp, Wq, bq, Wk, bk, Wv, bv, Q, Kb, Vb, sm, t);
    }
}

// ---------------------------------------------------------------------------
// Dispatch 2: split-Q attention with GROUP-BATCHED online softmax.
// Grid (NSEG, H, QS), block 256 = 64 query slots x 4 lanes (E/4 = 8 elems).
// Per key-group of 8: scores computed independently (shfls pipelined, out of
// the m/l chain), then one max/corr + 8 independent exps + tree-accumulate.
// ---------------------------------------------------------------------------
__global__ __launch_bounds__(ATPB) void attn_kernel(const float* __restrict__ Q,
                                                    const float* __restrict__ K,
                                                    const float* __restrict__ V,
                                                    const int* __restrict__ seg_rows,
                                                    const int* __restrict__ seg_off,
                                                    float* __restrict__ out) {
    __shared__ float Ks[CH * E];   // 16 KB
    __shared__ float Vs[CH * E];   // 16 KB
    __shared__ int   rid[CH];

    const int s   = blockIdx.x;
    const int h   = blockIdx.y;
    const int z   = blockIdx.z;
    const int beg = seg_off[s];
    const int len = seg_off[s + 1] - beg;
    const int t   = threadIdx.x;
    const float scale = 0.17677669529663687f;   // 1/sqrt(32)

    const int q0 = (int)(((long)len * z) / QS);
    const int q1 = (int)(((long)len * (z + 1)) / QS);

    const int ql = t & 3;    // E quarter: elems ql*8 .. ql*8+7
    const int qq = t >> 2;   // query slot in [0,64)

    const int nb = (q1 - q0 + 63) >> 6;   // normally 1 (len<=192)

    for (int b2 = 0; b2 < nb; ++b2) {
        const int  qi     = q0 + b2 * 64 + qq;
        const bool active = (qi < q1);
        const int  qrow   = active ? seg_rows[beg + qi] : 0;

        float q[8];
        {
            const float* qp = Q + (size_t)qrow * P + h * E + ql * 8;
            float4 v0 = *(const float4*)(qp);
            float4 v1 = *(const float4*)(qp + 4);
            q[0] = v0.x; q[1] = v0.y; q[2] = v0.z; q[3] = v0.w;
            q[4] = v1.x; q[5] = v1.y; q[6] = v1.z; q[7] = v1.w;
        }

        float m = NEGF, l = 0.f;
        float acc[8];
#pragma unroll
        for (int e = 0; e < 8; ++e) acc[e] = 0.f;

        for (int cb = 0; cb < len; cb += CH) {
            const int cl = min(CH, len - cb);
            __syncthreads();
            if (t < cl) rid[t] = seg_rows[beg + cb + t];
            __syncthreads();
            for (int idx = t; idx < cl * E; idx += ATPB) {
                const int r = idx >> 5, e = idx & 31;
                const int krow = rid[r];
                Ks[idx] = K[(size_t)krow * P + h * E + e];
                Vs[idx] = V[(size_t)krow * P + h * E + e];
            }
            __syncthreads();

            for (int g = 0; g < cl; g += G) {
                // --- phase 1: 8 independent scores (shfls pipelined) ---
                float sc[G];
                int   rc[G];
#pragma unroll
                for (int i = 0; i < G; ++i) {
                    const int r = g + i;
                    rc[i] = (r < cl) ? r : (cl - 1);     // clamp, masked below
                    const float* kr = Ks + rc[i] * E + ql * 8;
                    float4 a0 = *(const float4*)(kr);
                    float4 a1 = *(const float4*)(kr + 4);
                    float d0 = q[0] * a0.x + q[4] * a1.x;
                    float d1 = q[1] * a0.y + q[5] * a1.y;
                    float d2 = q[2] * a0.z + q[6] * a1.z;
                    float d3 = q[3] * a0.w + q[7] * a1.w;
                    float d  = (d0 + d1) + (d2 + d3);
                    d += __shfl_xor(d, 1);
                    d += __shfl_xor(d, 2);               // full dot over 4 lanes
                    sc[i] = (r < cl) ? d * scale : NEGF; // masked -> p = 0
                }
                // --- phase 2: one group max + corr ---
                float g0 = fmaxf(fmaxf(sc[0], sc[1]), fmaxf(sc[2], sc[3]));
                float g1 = fmaxf(fmaxf(sc[4], sc[5]), fmaxf(sc[6], sc[7]));
                const float mn   = fmaxf(m, fmaxf(g0, g1));
                const float corr = __expf(m - mn);
                m = mn;
                // --- phase 3: 8 independent exps ---
                float p[G];
#pragma unroll
                for (int i = 0; i < G; ++i) p[i] = __expf(sc[i] - mn);
                const float sp = ((p[0] + p[1]) + (p[2] + p[3]))
                               + ((p[4] + p[5]) + (p[6] + p[7]));
                l = fmaf(l, corr, sp);
                // --- phase 4: rescale acc once, then 8-deep FMA trees ---
#pragma unroll
                for (int e = 0; e < 8; ++e) acc[e] *= corr;
#pragma unroll
                for (int i = 0; i < G; ++i) {
                    const float* vr = Vs + rc[i] * E + ql * 8;
                    const float pi = p[i];
                    float4 v0 = *(const float4*)(vr);
                    float4 v1 = *(const float4*)(vr + 4);
                    acc[0] = fmaf(pi, v0.x, acc[0]);
                    acc[1] = fmaf(pi, v0.y, acc[1]);
                    acc[2] = fmaf(pi, v0.z, acc[2]);
                    acc[3] = fmaf(pi, v0.w, acc[3]);
                    acc[4] = fmaf(pi, v1.x, acc[4]);
                    acc[5] = fmaf(pi, v1.y, acc[5]);
                    acc[6] = fmaf(pi, v1.z, acc[6]);
                    acc[7] = fmaf(pi, v1.w, acc[7]);
                }
            }
        }

        if (active) {
            const float inv = 1.0f / l;
            float* op = out + (size_t)qrow * P + h * E + ql * 8;
            *(float4*)(op)     = make_float4(acc[0] * inv, acc[1] * inv, acc[2] * inv, acc[3] * inv);
            *(float4*)(op + 4) = make_float4(acc[4] * inv, acc[5] * inv, acc[6] * inv, acc[7] * inv);
        }
    }
}

// ---------------------------------------------------------------------------
extern "C" void kernel_launch(void* const* d_in, const int* in_sizes, int n_in,
                              void* d_out, int out_size, void* d_ws, size_t ws_size,
                              hipStream_t stream) {
    const float* inp = (const float*)d_in[0];
    const int*   pos = (const int*)d_in[1];
    const float* Wq  = (const float*)d_in[2];
    const float* bq  = (const float*)d_in[3];
    const float* Wk  = (const float*)d_in[4];
    const float* bk  = (const float*)d_in[5];
    const float* Wv  = (const float*)d_in[6];
    const float* bv  = (const float*)d_in[7];
    float* out = (float*)d_out;

    float* Q  = (float*)d_ws;
    float* Kb = Q + (size_t)N * P;
    float* Vb = Kb + (size_t)N * P;
    int* seg_rows = (int*)(Vb + (size_t)N * P);
    int* seg_off  = seg_rows + N;          // NSEG+1

    sort_proj_kernel<<<1 + PROJ_TASKS, TPB, 0, stream>>>(
        inp, pos, Wq, bq, Wk, bk, Wv, bv, Q, Kb, Vb, seg_rows, seg_off);

    attn_kernel<<<dim3(NSEG, H, QS), ATPB, 0, stream>>>(
        Q, Kb, Vb, seg_rows, seg_off, out);
}